// Round 1
// baseline (299.795 us; speedup 1.0000x reference)
//
#include <hip/hip_runtime.h>

typedef __bf16 bf16x8 __attribute__((ext_vector_type(8)));
typedef float  f32x4  __attribute__((ext_vector_type(4)));
typedef unsigned short u16;
typedef u16 u16x8 __attribute__((ext_vector_type(8)));

#define MFMA16(a, b, c) __builtin_amdgcn_mfma_f32_16x16x32_bf16((a), (b), (c), 0, 0, 0)

__device__ __forceinline__ u16 f2bf(float f) {
  __bf16 b = (__bf16)f;
  return __builtin_bit_cast(u16, b);
}
__device__ __forceinline__ bf16x8 ld_bf8(const u16* p) {
  return __builtin_bit_cast(bf16x8, *(const u16x8*)p);
}

// ---------------------------------------------------------------- cvt x -> bf16
__global__ __launch_bounds__(256) void k_cvt_x(const float4* __restrict__ x,
                                               ushort4* __restrict__ xb) {
  int i = blockIdx.x * 256 + threadIdx.x;
  float4 v = x[i];
  ushort4 o;
  o.x = f2bf(v.x); o.y = f2bf(v.y); o.z = f2bf(v.z); o.w = f2bf(v.w);
  xb[i] = o;
}

// ------------------------------------- transpose weights: fp32 [K][N] -> bf16 [N][K]
// concatenated out-rows: [0,1024)=Wq  [1024,1280)=Wk  [1280,1536)=Wv  [1536,2560)=Wo
__global__ __launch_bounds__(256) void k_tw(const float* __restrict__ Wq,
                                            const float* __restrict__ Wk,
                                            const float* __restrict__ Wv,
                                            const float* __restrict__ Wo,
                                            u16* __restrict__ WqkvT,
                                            u16* __restrict__ WoT) {
  __shared__ float t[64][65];
  int n0 = blockIdx.x * 64, k0 = blockIdx.y * 64;
  int c = threadIdx.x & 63, r = threadIdx.x >> 6;
  int n = n0 + c;
  const float* sp; int stride; int nn;
  if (n < 1024)      { sp = Wq; stride = 1024; nn = n; }
  else if (n < 1280) { sp = Wk; stride = 256;  nn = n - 1024; }
  else if (n < 1536) { sp = Wv; stride = 256;  nn = n - 1280; }
  else               { sp = Wo; stride = 1024; nn = n - 1536; }
#pragma unroll
  for (int j = 0; j < 16; ++j)
    t[r + j * 4][c] = sp[(size_t)(k0 + r + j * 4) * stride + nn];
  __syncthreads();
#pragma unroll
  for (int j = 0; j < 16; ++j) {
    int rr = r + j * 4;
    int orow = n0 + rr;
    u16* d = (orow < 1536) ? (WqkvT + (size_t)orow * 1024)
                           : (WoT + (size_t)(orow - 1536) * 1024);
    d[k0 + c] = f2bf(t[c][rr]);
  }
}

// ---------------------------------------------------------------- GEMM (bf16 MFMA)
// C[M][N] (f32) = A[M][K] (bf16 row-major) * Bt[N][K]^T (bf16 row-major)
// 128x128 tile, BK=64, 4 waves (2x2), global_load_lds w=16, XOR-swizzled LDS.
__global__ __launch_bounds__(256) void k_gemm(const u16* __restrict__ A,
                                              const u16* __restrict__ Bt,
                                              float* __restrict__ C,
                                              int M, int N, int K) {
  __shared__ u16 lA[128 * 64];
  __shared__ u16 lB[128 * 64];
  const int t = threadIdx.x;
  const int lane = t & 63;
  const int w = t >> 6;
  const int lg = lane >> 4, lr = lane & 15;
  const int wr = w >> 1, wc = w & 1;
  const int m0 = blockIdx.y * 128, n0 = blockIdx.x * 128;

  f32x4 acc[4][4];
#pragma unroll
  for (int a = 0; a < 4; ++a)
#pragma unroll
    for (int b = 0; b < 4; ++b) acc[a][b] = (f32x4)0.0f;

  for (int kt = 0; kt < K; kt += 64) {
#pragma unroll
    for (int i = 0; i < 4; ++i) {
      int c = t + i * 256;
      int row = c >> 3, slot = c & 7;
      int k8 = (slot ^ (row & 7)) << 3;
      __builtin_amdgcn_global_load_lds(
          (const __attribute__((address_space(1))) void*)(A + (size_t)(m0 + row) * K + kt + k8),
          (__attribute__((address_space(3))) void*)(&lA[c * 8]), 16, 0, 0);
    }
#pragma unroll
    for (int i = 0; i < 4; ++i) {
      int c = t + i * 256;
      int row = c >> 3, slot = c & 7;
      int k8 = (slot ^ (row & 7)) << 3;
      __builtin_amdgcn_global_load_lds(
          (const __attribute__((address_space(1))) void*)(Bt + (size_t)(n0 + row) * K + kt + k8),
          (__attribute__((address_space(3))) void*)(&lB[c * 8]), 16, 0, 0);
    }
    asm volatile("s_waitcnt vmcnt(0)" ::: "memory");
    __syncthreads();

#pragma unroll
    for (int ks = 0; ks < 2; ++ks) {
      bf16x8 af[4], bff[4];
#pragma unroll
      for (int mf = 0; mf < 4; ++mf) {
        int row = wr * 64 + mf * 16 + lr;
        int eo = (ks * 32 + lg * 8) ^ ((row & 7) << 3);
        af[mf] = ld_bf8(&lA[row * 64 + eo]);
      }
#pragma unroll
      for (int nf = 0; nf < 4; ++nf) {
        int row = wc * 64 + nf * 16 + lr;
        int eo = (ks * 32 + lg * 8) ^ ((row & 7) << 3);
        bff[nf] = ld_bf8(&lB[row * 64 + eo]);
      }
#pragma unroll
      for (int mf = 0; mf < 4; ++mf)
#pragma unroll
        for (int nf = 0; nf < 4; ++nf)
          acc[mf][nf] = MFMA16(af[mf], bff[nf], acc[mf][nf]);
    }
    __syncthreads();
  }

#pragma unroll
  for (int mf = 0; mf < 4; ++mf)
#pragma unroll
    for (int nf = 0; nf < 4; ++nf) {
      int col = n0 + wc * 64 + nf * 16 + lr;
#pragma unroll
      for (int i = 0; i < 4; ++i) {
        int row = m0 + wr * 64 + mf * 16 + lg * 4 + i;
        C[(size_t)row * N + col] = acc[mf][nf][i];
      }
    }
}

// ---------------------------------------------------------------- RoPE (+scale on Q)
// QKV f32 [4096][1536] -> Qa bf16 [B][NH][S][HD], Ka bf16 [B][KVH][S][HD]
#define NTQ (2 * 2048 * 16 * 32)
__global__ __launch_bounds__(256) void k_rope(const float* __restrict__ QKV,
                                              u16* __restrict__ Qa,
                                              u16* __restrict__ Ka) {
  int tid = blockIdx.x * 256 + threadIdx.x;
  const float L2B = 13.287712379549449f / 32.f;  // log2(10000)/32
  if (tid < NTQ) {
    int j = tid & 31, h = (tid >> 5) & 15, s = (tid >> 9) & 2047, b = tid >> 20;
    const float* src = QKV + (size_t)((b << 11) + s) * 1536 + h * 64 + j;
    float q0 = src[0], q1 = src[32];
    float ang = (float)s * exp2f(-(float)j * L2B);
    float sn, cs; sincosf(ang, &sn, &cs);
    u16* dst = Qa + ((size_t)(b * 16 + h) * 2048 + s) * 64 + j;
    dst[0]  = f2bf((q0 * cs - q1 * sn) * 0.125f);
    dst[32] = f2bf((q1 * cs + q0 * sn) * 0.125f);
  } else {
    int t2 = tid - NTQ;
    int j = t2 & 31, kvh = (t2 >> 5) & 3, s = (t2 >> 7) & 2047, b = t2 >> 18;
    const float* src = QKV + (size_t)((b << 11) + s) * 1536 + 1024 + kvh * 64 + j;
    float k0 = src[0], k1 = src[32];
    float ang = (float)s * exp2f(-(float)j * L2B);
    float sn, cs; sincosf(ang, &sn, &cs);
    u16* dst = Ka + ((size_t)(b * 4 + kvh) * 2048 + s) * 64 + j;
    dst[0]  = f2bf(k0 * cs - k1 * sn);
    dst[32] = f2bf(k1 * cs + k0 * sn);
  }
}

// ------------------------------------ V transpose: QKV cols [1280,1536) -> Vt [B][KVH][HD][S]
__global__ __launch_bounds__(256) void k_tv(const float* __restrict__ QKV,
                                            u16* __restrict__ Vt) {
  __shared__ float t[64][65];
  int cb = blockIdx.x;          // kv head (64-col block)
  int r0 = blockIdx.y * 64;     // global row (b,s)
  int b = r0 >> 11, s0 = r0 & 2047;
  int c = threadIdx.x & 63, r = threadIdx.x >> 6;
#pragma unroll
  for (int j = 0; j < 16; ++j)
    t[r + j * 4][c] = QKV[(size_t)(r0 + r + j * 4) * 1536 + 1280 + cb * 64 + c];
  __syncthreads();
#pragma unroll
  for (int j = 0; j < 16; ++j) {
    int rr = r + j * 4;
    Vt[((size_t)(b * 4 + cb) * 64 + rr) * 2048 + s0 + c] = f2bf(t[c][rr]);
  }
}

// ---------------------------------------------------------------- flash attention
// grid (qt=32, h=16, b=2), 256 threads = 4 waves, wave owns 16 Q rows.
__global__ __launch_bounds__(256) void k_attn(const u16* __restrict__ Qa,
                                              const u16* __restrict__ Ka,
                                              const u16* __restrict__ Vt,
                                              u16* __restrict__ Ob) {
  __shared__ u16 plds[4][512];
  int qt = blockIdx.x, h = blockIdx.y, b = blockIdx.z;
  int lane = threadIdx.x & 63, w = threadIdx.x >> 6;
  int lg = lane >> 4, lr = lane & 15;
  int q0 = qt * 64 + w * 16;
  int kvh = h >> 2;
  const u16* Qp = Qa + ((size_t)(b * 16 + h) * 2048 + q0) * 64;
  const u16* Kp = Ka + ((size_t)(b * 4 + kvh) * 2048) * 64;
  const u16* Vp = Vt + ((size_t)(b * 4 + kvh) * 64) * 2048;
  u16* myp = plds[w];

  bf16x8 aq0 = ld_bf8(Qp + lr * 64 + lg * 8);
  bf16x8 aq1 = ld_bf8(Qp + lr * 64 + 32 + lg * 8);

  f32x4 o[4];
#pragma unroll
  for (int nf = 0; nf < 4; ++nf) o[nf] = (f32x4)0.0f;
  float m[4], lsum[4];
#pragma unroll
  for (int i = 0; i < 4; ++i) { m[i] = -1e30f; lsum[i] = 0.f; }

  int ktend = (q0 + 15) >> 5;
  for (int kt = 0; kt <= ktend; ++kt) {
    int kbase = kt * 32;
    f32x4 sf0 = (f32x4)0.0f, sf1 = (f32x4)0.0f;
    {
      bf16x8 bk;
      bk = ld_bf8(Kp + (size_t)(kbase + lr) * 64 + lg * 8);           sf0 = MFMA16(aq0, bk, sf0);
      bk = ld_bf8(Kp + (size_t)(kbase + lr) * 64 + 32 + lg * 8);      sf0 = MFMA16(aq1, bk, sf0);
      bk = ld_bf8(Kp + (size_t)(kbase + 16 + lr) * 64 + lg * 8);      sf1 = MFMA16(aq0, bk, sf1);
      bk = ld_bf8(Kp + (size_t)(kbase + 16 + lr) * 64 + 32 + lg * 8); sf1 = MFMA16(aq1, bk, sf1);
    }
    if (kbase + 31 > q0) {
#pragma unroll
      for (int i = 0; i < 4; ++i) {
        int row = q0 + lg * 4 + i;
        if (kbase + lr > row)      sf0[i] = -1e30f;
        if (kbase + 16 + lr > row) sf1[i] = -1e30f;
      }
    }
#pragma unroll
    for (int i = 0; i < 4; ++i) {
      float mx = fmaxf(sf0[i], sf1[i]);
      mx = fmaxf(mx, __shfl_xor(mx, 1));
      mx = fmaxf(mx, __shfl_xor(mx, 2));
      mx = fmaxf(mx, __shfl_xor(mx, 4));
      mx = fmaxf(mx, __shfl_xor(mx, 8));
      float mnew = fmaxf(m[i], mx);
      float corr = __expf(m[i] - mnew);
      float p0 = __expf(sf0[i] - mnew);
      float p1 = __expf(sf1[i] - mnew);
      float rs = p0 + p1;
      rs += __shfl_xor(rs, 1);
      rs += __shfl_xor(rs, 2);
      rs += __shfl_xor(rs, 4);
      rs += __shfl_xor(rs, 8);
      lsum[i] = lsum[i] * corr + rs;
      m[i] = mnew;
#pragma unroll
      for (int nf = 0; nf < 4; ++nf) o[nf][i] *= corr;
      int row = lg * 4 + i;
      myp[row * 32 + (lr ^ ((row & 3) << 3))]        = f2bf(p0);
      myp[row * 32 + ((16 + lr) ^ ((row & 3) << 3))] = f2bf(p1);
    }
    asm volatile("s_waitcnt lgkmcnt(0)" ::: "memory");
    bf16x8 pa = ld_bf8(&myp[lr * 32 + ((lg * 8) ^ ((lr & 3) << 3))]);
#pragma unroll
    for (int nf = 0; nf < 4; ++nf) {
      bf16x8 bv = ld_bf8(Vp + (size_t)(nf * 16 + lr) * 2048 + kbase + lg * 8);
      o[nf] = MFMA16(pa, bv, o[nf]);
    }
  }

#pragma unroll
  for (int i = 0; i < 4; ++i) lsum[i] = 1.f / lsum[i];
#pragma unroll
  for (int nf = 0; nf < 4; ++nf)
#pragma unroll
    for (int i = 0; i < 4; ++i) {
      int row = q0 + lg * 4 + i;
      Ob[(size_t)(b * 2048 + row) * 1024 + h * 64 + nf * 16 + lr] = f2bf(o[nf][i] * lsum[i]);
    }
}

// ----------------------------------------------------------------------------
extern "C" void kernel_launch(void* const* d_in, const int* in_sizes, int n_in,
                              void* d_out, int out_size, void* d_ws, size_t ws_size,
                              hipStream_t stream) {
  const float* x  = (const float*)d_in[0];
  const float* Wq = (const float*)d_in[1];
  const float* Wk = (const float*)d_in[2];
  const float* Wv = (const float*)d_in[3];
  const float* Wo = (const float*)d_in[4];
  float* out = (float*)d_out;

  char* ws = (char*)d_ws;
  u16*   xb    = (u16*)(ws);                    //  8,388,608 B
  u16*   WqkvT = (u16*)(ws + 8388608);          //  3,145,728
  u16*   WoT   = (u16*)(ws + 11534336);         //  2,097,152
  float* QKV   = (float*)(ws + 13631488);       // 25,165,824
  u16*   Qa    = (u16*)(ws + 38797312);         //  8,388,608
  u16*   Ka    = (u16*)(ws + 47185920);         //  2,097,152
  u16*   Vt    = (u16*)(ws + 49283072);         //  2,097,152
  u16*   Ob    = (u16*)(ws + 51380224);         //  8,388,608  (end 59,768,832)

  k_cvt_x<<<4096, 256, 0, stream>>>((const float4*)x, (ushort4*)xb);
  k_tw<<<dim3(40, 16), 256, 0, stream>>>(Wq, Wk, Wv, Wo, WqkvT, WoT);
  k_gemm<<<dim3(12, 32), 256, 0, stream>>>(xb, WqkvT, QKV, 4096, 1536, 1024);
  k_rope<<<10240, 256, 0, stream>>>(QKV, Qa, Ka);
  k_tv<<<dim3(4, 64), 256, 0, stream>>>(QKV, Vt);
  k_attn<<<dim3(32, 16, 2), 256, 0, stream>>>(Qa, Ka, Vt, Ob);
  k_gemm<<<dim3(8, 32), 256, 0, stream>>>(Ob, WoT, out, 4096, 1024, 1024);
}

// Round 2
// 148.022 us; speedup vs baseline: 2.0253x; 2.0253x over previous
//
#include <hip/hip_runtime.h>

typedef __bf16 bf16x8 __attribute__((ext_vector_type(8)));
typedef float  f32x4  __attribute__((ext_vector_type(4)));
typedef float  f32x16 __attribute__((ext_vector_type(16)));
typedef unsigned short u16;
typedef unsigned int u32;
typedef u16 u16x8 __attribute__((ext_vector_type(8)));
typedef u32 u32x4 __attribute__((ext_vector_type(4)));

#define MFMA16(a, b, c) __builtin_amdgcn_mfma_f32_16x16x32_bf16((a), (b), (c), 0, 0, 0)
#define MFMA32(a, b, c) __builtin_amdgcn_mfma_f32_32x32x16_bf16((a), (b), (c), 0, 0, 0)

__device__ __forceinline__ u16 f2bf(float f) {
  __bf16 b = (__bf16)f;
  return __builtin_bit_cast(u16, b);
}
__device__ __forceinline__ bf16x8 ld_bf8(const u16* p) {
  return __builtin_bit_cast(bf16x8, *(const u16x8*)p);
}

// ---------------------------------------------------------------- cvt x -> bf16
__global__ __launch_bounds__(256) void k_cvt_x(const float4* __restrict__ x,
                                               ushort4* __restrict__ xb) {
  int i = blockIdx.x * 256 + threadIdx.x;
  float4 v = x[i];
  ushort4 o;
  o.x = f2bf(v.x); o.y = f2bf(v.y); o.z = f2bf(v.z); o.w = f2bf(v.w);
  xb[i] = o;
}

// ------------------------------------- transpose weights: fp32 [K][N] -> bf16 [N][K]
__global__ __launch_bounds__(256) void k_tw(const float* __restrict__ Wq,
                                            const float* __restrict__ Wk,
                                            const float* __restrict__ Wv,
                                            const float* __restrict__ Wo,
                                            u16* __restrict__ WqkvT,
                                            u16* __restrict__ WoT) {
  __shared__ float t[64][65];
  int n0 = blockIdx.x * 64, k0 = blockIdx.y * 64;
  int c = threadIdx.x & 63, r = threadIdx.x >> 6;
  int n = n0 + c;
  const float* sp; int stride; int nn;
  if (n < 1024)      { sp = Wq; stride = 1024; nn = n; }
  else if (n < 1280) { sp = Wk; stride = 256;  nn = n - 1024; }
  else if (n < 1536) { sp = Wv; stride = 256;  nn = n - 1280; }
  else               { sp = Wo; stride = 1024; nn = n - 1536; }
#pragma unroll
  for (int j = 0; j < 16; ++j)
    t[r + j * 4][c] = sp[(size_t)(k0 + r + j * 4) * stride + nn];
  __syncthreads();
#pragma unroll
  for (int j = 0; j < 16; ++j) {
    int rr = r + j * 4;
    int orow = n0 + rr;
    u16* d = (orow < 1536) ? (WqkvT + (size_t)orow * 1024)
                           : (WoT + (size_t)(orow - 1536) * 1024);
    d[k0 + c] = f2bf(t[c][rr]);
  }
}

// ---------------------------------------------------------------- GEMM (bf16 MFMA)
__global__ __launch_bounds__(256) void k_gemm(const u16* __restrict__ A,
                                              const u16* __restrict__ Bt,
                                              float* __restrict__ C,
                                              int M, int N, int K) {
  __shared__ u16 lA[128 * 64];
  __shared__ u16 lB[128 * 64];
  const int t = threadIdx.x;
  const int lane = t & 63;
  const int w = t >> 6;
  const int lg = lane >> 4, lr = lane & 15;
  const int wr = w >> 1, wc = w & 1;
  const int m0 = blockIdx.y * 128, n0 = blockIdx.x * 128;

  f32x4 acc[4][4];
#pragma unroll
  for (int a = 0; a < 4; ++a)
#pragma unroll
    for (int b = 0; b < 4; ++b) acc[a][b] = (f32x4)0.0f;

  for (int kt = 0; kt < K; kt += 64) {
#pragma unroll
    for (int i = 0; i < 4; ++i) {
      int c = t + i * 256;
      int row = c >> 3, slot = c & 7;
      int k8 = (slot ^ (row & 7)) << 3;
      __builtin_amdgcn_global_load_lds(
          (const __attribute__((address_space(1))) void*)(A + (size_t)(m0 + row) * K + kt + k8),
          (__attribute__((address_space(3))) void*)(&lA[c * 8]), 16, 0, 0);
    }
#pragma unroll
    for (int i = 0; i < 4; ++i) {
      int c = t + i * 256;
      int row = c >> 3, slot = c & 7;
      int k8 = (slot ^ (row & 7)) << 3;
      __builtin_amdgcn_global_load_lds(
          (const __attribute__((address_space(1))) void*)(Bt + (size_t)(n0 + row) * K + kt + k8),
          (__attribute__((address_space(3))) void*)(&lB[c * 8]), 16, 0, 0);
    }
    asm volatile("s_waitcnt vmcnt(0)" ::: "memory");
    __syncthreads();

#pragma unroll
    for (int ks = 0; ks < 2; ++ks) {
      bf16x8 af[4], bff[4];
#pragma unroll
      for (int mf = 0; mf < 4; ++mf) {
        int row = wr * 64 + mf * 16 + lr;
        int eo = (ks * 32 + lg * 8) ^ ((row & 7) << 3);
        af[mf] = ld_bf8(&lA[row * 64 + eo]);
      }
#pragma unroll
      for (int nf = 0; nf < 4; ++nf) {
        int row = wc * 64 + nf * 16 + lr;
        int eo = (ks * 32 + lg * 8) ^ ((row & 7) << 3);
        bff[nf] = ld_bf8(&lB[row * 64 + eo]);
      }
#pragma unroll
      for (int mf = 0; mf < 4; ++mf)
#pragma unroll
        for (int nf = 0; nf < 4; ++nf)
          acc[mf][nf] = MFMA16(af[mf], bff[nf], acc[mf][nf]);
    }
    __syncthreads();
  }

#pragma unroll
  for (int mf = 0; mf < 4; ++mf)
#pragma unroll
    for (int nf = 0; nf < 4; ++nf) {
      int col = n0 + wc * 64 + nf * 16 + lr;
#pragma unroll
      for (int i = 0; i < 4; ++i) {
        int row = m0 + wr * 64 + mf * 16 + lg * 4 + i;
        C[(size_t)row * N + col] = acc[mf][nf][i];
      }
    }
}

// ---------------------------------------------------------------- RoPE (+scale on Q)
#define NTQ (2 * 2048 * 16 * 32)
__global__ __launch_bounds__(256) void k_rope(const float* __restrict__ QKV,
                                              u16* __restrict__ Qa,
                                              u16* __restrict__ Ka) {
  int tid = blockIdx.x * 256 + threadIdx.x;
  const float L2B = 13.287712379549449f / 32.f;  // log2(10000)/32
  if (tid < NTQ) {
    int j = tid & 31, h = (tid >> 5) & 15, s = (tid >> 9) & 2047, b = tid >> 20;
    const float* src = QKV + (size_t)((b << 11) + s) * 1536 + h * 64 + j;
    float q0 = src[0], q1 = src[32];
    float ang = (float)s * exp2f(-(float)j * L2B);
    float sn, cs; sincosf(ang, &sn, &cs);
    u16* dst = Qa + ((size_t)(b * 16 + h) * 2048 + s) * 64 + j;
    dst[0]  = f2bf((q0 * cs - q1 * sn) * 0.125f);
    dst[32] = f2bf((q1 * cs + q0 * sn) * 0.125f);
  } else {
    int t2 = tid - NTQ;
    int j = t2 & 31, kvh = (t2 >> 5) & 3, s = (t2 >> 7) & 2047, b = t2 >> 18;
    const float* src = QKV + (size_t)((b << 11) + s) * 1536 + 1024 + kvh * 64 + j;
    float k0 = src[0], k1 = src[32];
    float ang = (float)s * exp2f(-(float)j * L2B);
    float sn, cs; sincosf(ang, &sn, &cs);
    u16* dst = Ka + ((size_t)(b * 4 + kvh) * 2048 + s) * 64 + j;
    dst[0]  = f2bf(k0 * cs - k1 * sn);
    dst[32] = f2bf(k1 * cs + k0 * sn);
  }
}

// ------------------------------------ V transpose -> Vt [B][KVH][HD][S]
__global__ __launch_bounds__(256) void k_tv(const float* __restrict__ QKV,
                                            u16* __restrict__ Vt) {
  __shared__ float t[64][65];
  int cb = blockIdx.x;
  int r0 = blockIdx.y * 64;
  int b = r0 >> 11, s0 = r0 & 2047;
  int c = threadIdx.x & 63, r = threadIdx.x >> 6;
#pragma unroll
  for (int j = 0; j < 16; ++j)
    t[r + j * 4][c] = QKV[(size_t)(r0 + r + j * 4) * 1536 + 1280 + cb * 64 + c];
  __syncthreads();
#pragma unroll
  for (int j = 0; j < 16; ++j) {
    int rr = r + j * 4;
    Vt[((size_t)(b * 4 + cb) * 64 + rr) * 2048 + s0 + c] = f2bf(t[c][rr]);
  }
}

// ---------------------------------------------------------------- flash attention v2
// 1 wave per block, wave owns 32 q-rows. Swapped QK^T: S^T[kv][q] so lane = q-row.
// Swapped PV: O^T[d][q] keeps q in lane dim. No LDS, no barriers.
#define LOADKV(KF, VF, BASE) do {                                        \
    const u16* kp_ = Kp + (size_t)((BASE) + ql) * 64 + hi * 8;           \
    KF[0] = ld_bf8(kp_);      KF[1] = ld_bf8(kp_ + 16);                  \
    KF[2] = ld_bf8(kp_ + 32); KF[3] = ld_bf8(kp_ + 48);                  \
    const u16* vp_ = Vp + (size_t)ql * 2048 + (BASE) + hi * 8;           \
    VF[0] = ld_bf8(vp_);             VF[1] = ld_bf8(vp_ + 16);           \
    VF[2] = ld_bf8(vp_ + 32 * 2048); VF[3] = ld_bf8(vp_ + 32 * 2048 + 16); \
  } while (0)

#define PK2(a, b) ((u32)f2bf(a) | ((u32)f2bf(b) << 16))

#define TILE(KF, VF, DIAG) do {                                          \
    f32x16 s_ = (f32x16)0.0f;                                            \
    s_ = MFMA32(KF[0], qf0, s_);                                         \
    s_ = MFMA32(KF[1], qf1, s_);                                         \
    s_ = MFMA32(KF[2], qf2, s_);                                         \
    s_ = MFMA32(KF[3], qf3, s_);                                         \
    if (DIAG) {                                                          \
      _Pragma("unroll")                                                  \
      for (int r = 0; r < 16; ++r) {                                     \
        int kvo = (r & 3) + 8 * (r >> 2) + 4 * hi;                       \
        if (kvo > ql) s_[r] = -1e30f;                                    \
      }                                                                  \
    }                                                                    \
    float mt = s_[0];                                                    \
    _Pragma("unroll")                                                    \
    for (int r = 1; r < 16; ++r) mt = fmaxf(mt, s_[r]);                  \
    mt = fmaxf(mt, __shfl_xor(mt, 32));                                  \
    if (!__all(mt <= m + 8.f)) {                                         \
      float mn = fmaxf(m, mt);                                           \
      float corr = __expf(m - mn);                                       \
      l *= corr;                                                         \
      _Pragma("unroll")                                                  \
      for (int r = 0; r < 16; ++r) { o0[r] *= corr; o1[r] *= corr; }     \
      m = mn;                                                            \
    }                                                                    \
    float p_[16]; float ss = 0.f;                                        \
    _Pragma("unroll")                                                    \
    for (int r = 0; r < 16; ++r) { p_[r] = __expf(s_[r] - m); ss += p_[r]; } \
    ss += __shfl_xor(ss, 32);                                            \
    l += ss;                                                             \
    u32 a0 = PK2(p_[0], p_[1]),   a1 = PK2(p_[2], p_[3]);                \
    u32 a2 = PK2(p_[4], p_[5]),   a3 = PK2(p_[6], p_[7]);                \
    u32 c0 = PK2(p_[8], p_[9]),   c1 = PK2(p_[10], p_[11]);              \
    u32 c2 = PK2(p_[12], p_[13]), c3 = PK2(p_[14], p_[15]);              \
    u32 b0 = __shfl_xor(a0, 32), b1 = __shfl_xor(a1, 32);                \
    u32 b2 = __shfl_xor(a2, 32), b3 = __shfl_xor(a3, 32);                \
    u32 d0 = __shfl_xor(c0, 32), d1 = __shfl_xor(c1, 32);                \
    u32 d2 = __shfl_xor(c2, 32), d3 = __shfl_xor(c3, 32);                \
    u32x4 w0, w1;                                                        \
    w0.x = hi ? b2 : a0; w0.y = hi ? b3 : a1;                            \
    w0.z = hi ? a2 : b0; w0.w = hi ? a3 : b1;                            \
    w1.x = hi ? d2 : c0; w1.y = hi ? d3 : c1;                            \
    w1.z = hi ? c2 : d0; w1.w = hi ? c3 : d1;                            \
    bf16x8 pf0 = __builtin_bit_cast(bf16x8, w0);                         \
    bf16x8 pf1 = __builtin_bit_cast(bf16x8, w1);                         \
    o0 = MFMA32(VF[0], pf0, o0);                                         \
    o0 = MFMA32(VF[1], pf1, o0);                                         \
    o1 = MFMA32(VF[2], pf0, o1);                                         \
    o1 = MFMA32(VF[3], pf1, o1);                                         \
  } while (0)

__global__ __launch_bounds__(64) void k_attn(const u16* __restrict__ Qa,
                                             const u16* __restrict__ Ka,
                                             const u16* __restrict__ Vt,
                                             u16* __restrict__ Ob) {
  const int bx = blockIdx.x;
  const int tq = 63 - (bx >> 5);        // q-tile index, longest work first
  const int bh = bx & 31;
  const int h = bh & 15, b = bh >> 4;
  const int kvh = h >> 2;
  const int lane = threadIdx.x & 63;
  const int ql = lane & 31;             // q-row within tile (C col)
  const int hi = lane >> 5;
  const int q0 = tq * 32;

  const u16* Qp = Qa + ((size_t)(b * 16 + h) * 2048 + q0) * 64;
  const u16* Kp = Ka + (size_t)(b * 4 + kvh) * 2048 * 64;
  const u16* Vp = Vt + (size_t)(b * 4 + kvh) * 64 * 2048;

  bf16x8 qf0, qf1, qf2, qf3;  // B-operand: Q^T[d][q], lane holds q=ql, d=c*16+hi*8..
  {
    const u16* qp = Qp + ql * 64 + hi * 8;
    qf0 = ld_bf8(qp);      qf1 = ld_bf8(qp + 16);
    qf2 = ld_bf8(qp + 32); qf3 = ld_bf8(qp + 48);
  }

  f32x16 o0 = (f32x16)0.0f, o1 = (f32x16)0.0f;  // O^T[d][q], col=q=ql
  float m = -1e30f, l = 0.f;

  bf16x8 ka[4], va[4], kb2[4], vb2[4];
  LOADKV(ka, va, 0);
  int cur = 0;
  for (;;) {
    int nxt = cur + 32;
    if (nxt <= q0) LOADKV(kb2, vb2, nxt);
    TILE(ka, va, cur == q0);
    if (nxt > q0) break;
    cur = nxt; nxt += 32;
    if (nxt <= q0) LOADKV(ka, va, nxt);
    TILE(kb2, vb2, cur == q0);
    if (nxt > q0) break;
    cur = nxt;
  }

  float li = 1.f / l;
  u16* op = Ob + ((size_t)(b * 2048 + q0 + ql)) * 1024 + h * 64 + hi * 4;
#pragma unroll
  for (int g = 0; g < 4; ++g) {
    ushort4 w;
    w.x = f2bf(o0[g * 4 + 0] * li); w.y = f2bf(o0[g * 4 + 1] * li);
    w.z = f2bf(o0[g * 4 + 2] * li); w.w = f2bf(o0[g * 4 + 3] * li);
    *(ushort4*)(op + g * 8) = w;
  }
#pragma unroll
  for (int g = 0; g < 4; ++g) {
    ushort4 w;
    w.x = f2bf(o1[g * 4 + 0] * li); w.y = f2bf(o1[g * 4 + 1] * li);
    w.z = f2bf(o1[g * 4 + 2] * li); w.w = f2bf(o1[g * 4 + 3] * li);
    *(ushort4*)(op + 32 + g * 8) = w;
  }
}

// ----------------------------------------------------------------------------
extern "C" void kernel_launch(void* const* d_in, const int* in_sizes, int n_in,
                              void* d_out, int out_size, void* d_ws, size_t ws_size,
                              hipStream_t stream) {
  const float* x  = (const float*)d_in[0];
  const float* Wq = (const float*)d_in[1];
  const float* Wk = (const float*)d_in[2];
  const float* Wv = (const float*)d_in[3];
  const float* Wo = (const float*)d_in[4];
  float* out = (float*)d_out;

  char* ws = (char*)d_ws;
  u16*   xb    = (u16*)(ws);
  u16*   WqkvT = (u16*)(ws + 8388608);
  u16*   WoT   = (u16*)(ws + 11534336);
  float* QKV   = (float*)(ws + 13631488);
  u16*   Qa    = (u16*)(ws + 38797312);
  u16*   Ka    = (u16*)(ws + 47185920);
  u16*   Vt    = (u16*)(ws + 49283072);
  u16*   Ob    = (u16*)(ws + 51380224);

  k_cvt_x<<<4096, 256, 0, stream>>>((const float4*)x, (ushort4*)xb);
  k_tw<<<dim3(40, 16), 256, 0, stream>>>(Wq, Wk, Wv, Wo, WqkvT, WoT);
  k_gemm<<<dim3(12, 32), 256, 0, stream>>>(xb, WqkvT, QKV, 4096, 1536, 1024);
  k_rope<<<10240, 256, 0, stream>>>(QKV, Qa, Ka);
  k_tv<<<dim3(4, 64), 256, 0, stream>>>(QKV, Vt);
  k_attn<<<2048, 64, 0, stream>>>(Qa, Ka, Vt, Ob);
  k_gemm<<<dim3(8, 32), 256, 0, stream>>>(Ob, WoT, out, 4096, 1024, 1024);
}

// Round 3
// 142.615 us; speedup vs baseline: 2.1021x; 1.0379x over previous
//
#include <hip/hip_runtime.h>

typedef __bf16 bf16x8 __attribute__((ext_vector_type(8)));
typedef float  f32x4  __attribute__((ext_vector_type(4)));
typedef float  f32x16 __attribute__((ext_vector_type(16)));
typedef unsigned short u16;
typedef unsigned int u32;
typedef u16 u16x8 __attribute__((ext_vector_type(8)));
typedef u32 u32x4 __attribute__((ext_vector_type(4)));

#define MFMA16(a, b, c) __builtin_amdgcn_mfma_f32_16x16x32_bf16((a), (b), (c), 0, 0, 0)
#define MFMA32(a, b, c) __builtin_amdgcn_mfma_f32_32x32x16_bf16((a), (b), (c), 0, 0, 0)

__device__ __forceinline__ u16 f2bf(float f) {
  __bf16 b = (__bf16)f;
  return __builtin_bit_cast(u16, b);
}
__device__ __forceinline__ bf16x8 ld_bf8(const u16* p) {
  return __builtin_bit_cast(bf16x8, *(const u16x8*)p);
}

// ---------------------------------------------------------------- prep
// blocks [0,4096): cvt x->bf16 ; [4096,4736): transpose weights ; [4736,4992): sincos tab
__global__ __launch_bounds__(256) void k_prep(const float4* __restrict__ x,
                                              ushort4* __restrict__ xb,
                                              const float* __restrict__ Wq,
                                              const float* __restrict__ Wk,
                                              const float* __restrict__ Wv,
                                              const float* __restrict__ Wo,
                                              u16* __restrict__ WqkvT,
                                              u16* __restrict__ WoT,
                                              float2* __restrict__ tab) {
  __shared__ float t[64][65];
  int bid = blockIdx.x;
  if (bid < 4096) {
    int i = bid * 256 + threadIdx.x;
    float4 v = x[i];
    ushort4 o;
    o.x = f2bf(v.x); o.y = f2bf(v.y); o.z = f2bf(v.z); o.w = f2bf(v.w);
    xb[i] = o;
  } else if (bid < 4736) {
    int tb = bid - 4096;
    int n0 = (tb % 40) * 64, k0 = (tb / 40) * 64;
    int c = threadIdx.x & 63, r = threadIdx.x >> 6;
    int n = n0 + c;
    const float* sp; int stride; int nn;
    if (n < 1024)      { sp = Wq; stride = 1024; nn = n; }
    else if (n < 1280) { sp = Wk; stride = 256;  nn = n - 1024; }
    else if (n < 1536) { sp = Wv; stride = 256;  nn = n - 1280; }
    else               { sp = Wo; stride = 1024; nn = n - 1536; }
#pragma unroll
    for (int j = 0; j < 16; ++j)
      t[r + j * 4][c] = sp[(size_t)(k0 + r + j * 4) * stride + nn];
    __syncthreads();
#pragma unroll
    for (int j = 0; j < 16; ++j) {
      int rr = r + j * 4;
      int orow = n0 + rr;
      u16* d = (orow < 1536) ? (WqkvT + (size_t)orow * 1024)
                             : (WoT + (size_t)(orow - 1536) * 1024);
      d[k0 + c] = f2bf(t[c][rr]);
    }
  } else {
    int idx = (bid - 4736) * 256 + threadIdx.x;  // [0, 65536)
    int s = idx >> 5, j = idx & 31;
    const float L2B = 13.287712379549449f / 32.f;  // log2(10000)/32
    float ang = (float)s * exp2f(-(float)j * L2B);
    float sn, cs; sincosf(ang, &sn, &cs);
    tab[idx] = make_float2(cs, sn);
  }
}

// ---------------------------------------------------------------- GEMM1: QKV + fused RoPE
// C = xb[4096][1024] * WqkvT[1536][1024]^T ; epilogue writes Qa/Ka (rope'd bf16) and Vsd.
// Q pre-scaled by 0.125*log2(e) for the exp2 softmax.
__global__ __launch_bounds__(256) void k_gemm1(const u16* __restrict__ A,
                                               const u16* __restrict__ Bt,
                                               const float2* __restrict__ tab,
                                               u16* __restrict__ Qa,
                                               u16* __restrict__ Ka,
                                               u16* __restrict__ Vsd) {
  const int K = 1024;
  __shared__ u16 lA[128 * 64];
  __shared__ u16 lB[128 * 64];
  const int t = threadIdx.x;
  const int lane = t & 63;
  const int w = t >> 6;
  const int lg = lane >> 4, lr = lane & 15;
  const int wr = w >> 1, wc = w & 1;
  // XCD-aware swizzle: grid 384 = 12 n-blocks x 32 m-blocks
  int f = blockIdx.x;
  int cpx = 384 >> 3;
  int f2 = (f & 7) * cpx + (f >> 3);
  const int n0 = (f2 % 12) * 128, m0 = (f2 / 12) * 128;

  f32x4 acc[4][4];
#pragma unroll
  for (int a = 0; a < 4; ++a)
#pragma unroll
    for (int b = 0; b < 4; ++b) acc[a][b] = (f32x4)0.0f;

  for (int kt = 0; kt < K; kt += 64) {
#pragma unroll
    for (int i = 0; i < 4; ++i) {
      int c = t + i * 256;
      int row = c >> 3, slot = c & 7;
      int k8 = (slot ^ (row & 7)) << 3;
      __builtin_amdgcn_global_load_lds(
          (const __attribute__((address_space(1))) void*)(A + (size_t)(m0 + row) * K + kt + k8),
          (__attribute__((address_space(3))) void*)(&lA[c * 8]), 16, 0, 0);
    }
#pragma unroll
    for (int i = 0; i < 4; ++i) {
      int c = t + i * 256;
      int row = c >> 3, slot = c & 7;
      int k8 = (slot ^ (row & 7)) << 3;
      __builtin_amdgcn_global_load_lds(
          (const __attribute__((address_space(1))) void*)(Bt + (size_t)(n0 + row) * K + kt + k8),
          (__attribute__((address_space(3))) void*)(&lB[c * 8]), 16, 0, 0);
    }
    asm volatile("s_waitcnt vmcnt(0)" ::: "memory");
    __syncthreads();

#pragma unroll
    for (int ks = 0; ks < 2; ++ks) {
      bf16x8 af[4], bff[4];
#pragma unroll
      for (int mf = 0; mf < 4; ++mf) {
        int row = wr * 64 + mf * 16 + lr;
        int eo = (ks * 32 + lg * 8) ^ ((row & 7) << 3);
        af[mf] = ld_bf8(&lA[row * 64 + eo]);
      }
#pragma unroll
      for (int nf = 0; nf < 4; ++nf) {
        int row = wc * 64 + nf * 16 + lr;
        int eo = (ks * 32 + lg * 8) ^ ((row & 7) << 3);
        bff[nf] = ld_bf8(&lB[row * 64 + eo]);
      }
#pragma unroll
      for (int mf = 0; mf < 4; ++mf)
#pragma unroll
        for (int nf = 0; nf < 4; ++nf)
          acc[mf][nf] = MFMA16(af[mf], bff[nf], acc[mf][nf]);
    }
    __syncthreads();
  }

  const int colbase = n0 + wc * 64;  // multiple of 64
  if (colbase < 1280) {
    // Q or K: rope on pairs (nf, nf+2)
    const bool isQ = colbase < 1024;
    const float SC = isQ ? 0.18033688f : 1.0f;  // 0.125*log2(e) folded into Q
    u16* base;
    if (isQ) {
      int hh = colbase >> 6;
      base = Qa + (size_t)hh * 2048 * 64;        // + (b*16)*2048*64 later via row
    } else {
      int kvh = (colbase - 1024) >> 6;
      base = Ka + (size_t)kvh * 2048 * 64;
    }
    const int hstride = isQ ? 16 : 4;
#pragma unroll
    for (int mf = 0; mf < 4; ++mf)
#pragma unroll
      for (int i2 = 0; i2 < 4; ++i2) {
        int row = m0 + wr * 64 + mf * 16 + lg * 4 + i2;
        int bb = row >> 11, ss = row & 2047;
        float2 t0 = tab[ss * 32 + lr];
        float2 t1 = tab[ss * 32 + 16 + lr];
        float v0 = acc[mf][0][i2], v2 = acc[mf][2][i2];
        float v1 = acc[mf][1][i2], v3 = acc[mf][3][i2];
        u16* dst = base + ((size_t)bb * hstride * 2048 + ss) * 64;
        dst[lr]      = f2bf((v0 * t0.x - v2 * t0.y) * SC);
        dst[lr + 32] = f2bf((v2 * t0.x + v0 * t0.y) * SC);
        dst[lr + 16] = f2bf((v1 * t1.x - v3 * t1.y) * SC);
        dst[lr + 48] = f2bf((v3 * t1.x + v1 * t1.y) * SC);
      }
  } else {
    int kvh = (colbase - 1280) >> 6;
#pragma unroll
    for (int mf = 0; mf < 4; ++mf)
#pragma unroll
      for (int i2 = 0; i2 < 4; ++i2) {
        int row = m0 + wr * 64 + mf * 16 + lg * 4 + i2;
        int bb = row >> 11, ss = row & 2047;
        u16* dst = Vsd + ((size_t)(bb * 4 + kvh) * 2048 + ss) * 64;
#pragma unroll
        for (int nf = 0; nf < 4; ++nf) dst[nf * 16 + lr] = f2bf(acc[mf][nf][i2]);
      }
  }
}

// ------------------------------------ Vsd [bk][2048][64] -> Vt [bk][64][2048] (bf16)
__global__ __launch_bounds__(256) void k_tv2(const u16* __restrict__ Vsd,
                                             u16* __restrict__ Vt) {
  __shared__ u16 tl[64][72];
  int bk = blockIdx.x >> 5;
  int st = blockIdx.x & 31;
  int t = threadIdx.x;
  const u16* src = Vsd + ((size_t)bk * 2048 + st * 64) * 64;
#pragma unroll
  for (int p = 0; p < 2; ++p) {
    int rr = (t >> 3) + p * 32, ck = t & 7;
    *(u16x8*)&tl[rr][ck * 8] = *(const u16x8*)(src + rr * 64 + ck * 8);
  }
  __syncthreads();
  u16* dst = Vt + (size_t)bk * 64 * 2048 + st * 64;
#pragma unroll
  for (int p = 0; p < 2; ++p) {
    int dd = (t >> 3) + p * 32, ck = t & 7;
    u16x8 wv;
#pragma unroll
    for (int e = 0; e < 8; ++e) wv[e] = tl[ck * 8 + e][dd];
    *(u16x8*)(dst + (size_t)dd * 2048 + ck * 8) = wv;
  }
}

// ---------------------------------------------------------------- flash attention v3
// 1 wave/block, wave owns 64 q-rows (chains A,B of 32) sharing the K/V stream.
// No max tracking: p = exp2(s'), l = sum(p), O = P V, out = O/l. Masking only on
// the two peeled diagonal iterations.
#define LOADKV(KF, VF, BASE) do {                                        \
    const u16* kp_ = Kp + (size_t)((BASE) + ql) * 64 + hi * 8;           \
    KF[0] = ld_bf8(kp_);      KF[1] = ld_bf8(kp_ + 16);                  \
    KF[2] = ld_bf8(kp_ + 32); KF[3] = ld_bf8(kp_ + 48);                  \
    const u16* vp_ = Vp + (size_t)ql * 2048 + (BASE) + hi * 8;           \
    VF[0] = ld_bf8(vp_);             VF[1] = ld_bf8(vp_ + 16);           \
    VF[2] = ld_bf8(vp_ + 32 * 2048); VF[3] = ld_bf8(vp_ + 32 * 2048 + 16); \
  } while (0)

#define PK2(a, b) ((u32)f2bf(a) | ((u32)f2bf(b) << 16))

#define CHAIN(KF, VF, Q0, Q1, Q2, Q3, OL, OH, LL, DOMASK, QAD, KB) do {  \
    f32x16 s_ = (f32x16)0.0f;                                            \
    s_ = MFMA32(KF[0], Q0, s_);                                          \
    s_ = MFMA32(KF[1], Q1, s_);                                          \
    s_ = MFMA32(KF[2], Q2, s_);                                          \
    s_ = MFMA32(KF[3], Q3, s_);                                          \
    float p_[16];                                                        \
    if (DOMASK) {                                                        \
      _Pragma("unroll")                                                  \
      for (int r = 0; r < 16; ++r) {                                     \
        int kc = (KB) + (r & 3) + 8 * (r >> 2);                          \
        p_[r] = (kc > (QAD)) ? 0.f : exp2f(s_[r]);                       \
      }                                                                  \
    } else {                                                             \
      _Pragma("unroll")                                                  \
      for (int r = 0; r < 16; ++r) p_[r] = exp2f(s_[r]);                 \
    }                                                                    \
    float t0_ = p_[0] + p_[1], t1_ = p_[2] + p_[3];                      \
    float t2_ = p_[4] + p_[5], t3_ = p_[6] + p_[7];                      \
    float t4_ = p_[8] + p_[9], t5_ = p_[10] + p_[11];                    \
    float t6_ = p_[12] + p_[13], t7_ = p_[14] + p_[15];                  \
    t0_ += t1_; t2_ += t3_; t4_ += t5_; t6_ += t7_;                      \
    t0_ += t2_; t4_ += t6_;                                              \
    float ss_ = t0_ + t4_;                                               \
    ss_ += __shfl_xor(ss_, 32);                                          \
    LL += ss_;                                                           \
    u32 a0 = PK2(p_[0], p_[1]),   a1 = PK2(p_[2], p_[3]);                \
    u32 a2 = PK2(p_[4], p_[5]),   a3 = PK2(p_[6], p_[7]);                \
    u32 c0 = PK2(p_[8], p_[9]),   c1 = PK2(p_[10], p_[11]);              \
    u32 c2 = PK2(p_[12], p_[13]), c3 = PK2(p_[14], p_[15]);              \
    u32 b0 = __shfl_xor(a0, 32), b1 = __shfl_xor(a1, 32);                \
    u32 b2 = __shfl_xor(a2, 32), b3 = __shfl_xor(a3, 32);                \
    u32 d0 = __shfl_xor(c0, 32), d1 = __shfl_xor(c1, 32);                \
    u32 d2 = __shfl_xor(c2, 32), d3 = __shfl_xor(c3, 32);                \
    u32x4 w0, w1;                                                        \
    w0.x = hi ? b2 : a0; w0.y = hi ? b3 : a1;                            \
    w0.z = hi ? a2 : b0; w0.w = hi ? a3 : b1;                            \
    w1.x = hi ? d2 : c0; w1.y = hi ? d3 : c1;                            \
    w1.z = hi ? c2 : d0; w1.w = hi ? c3 : d1;                            \
    bf16x8 pf0 = __builtin_bit_cast(bf16x8, w0);                         \
    bf16x8 pf1 = __builtin_bit_cast(bf16x8, w1);                         \
    OL = MFMA32(VF[0], pf0, OL);                                         \
    OL = MFMA32(VF[1], pf1, OL);                                         \
    OH = MFMA32(VF[2], pf0, OH);                                         \
    OH = MFMA32(VF[3], pf1, OH);                                         \
  } while (0)

__global__ __launch_bounds__(64) void k_attn(const u16* __restrict__ Qa,
                                             const u16* __restrict__ Ka,
                                             const u16* __restrict__ Vt,
                                             u16* __restrict__ Ob) {
  const int bx = blockIdx.x;
  const int ii = 31 - (bx >> 5);        // dual-tile index, longest work first
  const int bh = bx & 31;
  const int h = bh & 15, b = bh >> 4;
  const int kvh = h >> 2;
  const int lane = threadIdx.x & 63;
  const int ql = lane & 31;
  const int hi = lane >> 5;
  const int q0A = ii * 64;
  const int q0B = q0A + 32;
  const int lastA = 2 * ii;
  const int lastB = lastA + 1;

  const u16* Qp = Qa + (size_t)(b * 16 + h) * 2048 * 64;
  const u16* Kp = Ka + (size_t)(b * 4 + kvh) * 2048 * 64;
  const u16* Vp = Vt + (size_t)(b * 4 + kvh) * 64 * 2048;

  bf16x8 qA0, qA1, qA2, qA3, qB0, qB1, qB2, qB3;
  {
    const u16* qp = Qp + (size_t)(q0A + ql) * 64 + hi * 8;
    qA0 = ld_bf8(qp);      qA1 = ld_bf8(qp + 16);
    qA2 = ld_bf8(qp + 32); qA3 = ld_bf8(qp + 48);
    qp += 32 * 64;
    qB0 = ld_bf8(qp);      qB1 = ld_bf8(qp + 16);
    qB2 = ld_bf8(qp + 32); qB3 = ld_bf8(qp + 48);
  }

  f32x16 oA0 = (f32x16)0.0f, oA1 = (f32x16)0.0f;
  f32x16 oB0 = (f32x16)0.0f, oB1 = (f32x16)0.0f;
  float lA = 0.f, lB = 0.f;
  const int qadA = q0A + ql - 4 * hi;
  const int qadB = q0B + ql - 4 * hi;

  bf16x8 ka[4], va[4], kb[4], vb[4];
  LOADKV(ka, va, 0);
  int j = 0;
  for (;;) {
    if (j == lastA) {
      LOADKV(kb, vb, lastB * 32);
      CHAIN(ka, va, qA0, qA1, qA2, qA3, oA0, oA1, lA, 1, qadA, lastA * 32);
      CHAIN(ka, va, qB0, qB1, qB2, qB3, oB0, oB1, lB, 0, 0, 0);
      CHAIN(kb, vb, qB0, qB1, qB2, qB3, oB0, oB1, lB, 1, qadB, lastB * 32);
      break;
    }
    LOADKV(kb, vb, (j + 1) * 32);
    CHAIN(ka, va, qA0, qA1, qA2, qA3, oA0, oA1, lA, 0, 0, 0);
    CHAIN(ka, va, qB0, qB1, qB2, qB3, oB0, oB1, lB, 0, 0, 0);
    j++;
    if (j == lastA) {
      LOADKV(ka, va, lastB * 32);
      CHAIN(kb, vb, qA0, qA1, qA2, qA3, oA0, oA1, lA, 1, qadA, lastA * 32);
      CHAIN(kb, vb, qB0, qB1, qB2, qB3, oB0, oB1, lB, 0, 0, 0);
      CHAIN(ka, va, qB0, qB1, qB2, qB3, oB0, oB1, lB, 1, qadB, lastB * 32);
      break;
    }
    LOADKV(ka, va, (j + 1) * 32);
    CHAIN(kb, vb, qA0, qA1, qA2, qA3, oA0, oA1, lA, 0, 0, 0);
    CHAIN(kb, vb, qB0, qB1, qB2, qB3, oB0, oB1, lB, 0, 0, 0);
    j++;
  }

  float liA = 1.f / lA, liB = 1.f / lB;
  u16* opA = Ob + ((size_t)(b * 2048 + q0A + ql)) * 1024 + h * 64 + hi * 4;
  u16* opB = Ob + ((size_t)(b * 2048 + q0B + ql)) * 1024 + h * 64 + hi * 4;
#pragma unroll
  for (int g = 0; g < 4; ++g) {
    ushort4 w;
    w.x = f2bf(oA0[g * 4 + 0] * liA); w.y = f2bf(oA0[g * 4 + 1] * liA);
    w.z = f2bf(oA0[g * 4 + 2] * liA); w.w = f2bf(oA0[g * 4 + 3] * liA);
    *(ushort4*)(opA + g * 8) = w;
    w.x = f2bf(oA1[g * 4 + 0] * liA); w.y = f2bf(oA1[g * 4 + 1] * liA);
    w.z = f2bf(oA1[g * 4 + 2] * liA); w.w = f2bf(oA1[g * 4 + 3] * liA);
    *(ushort4*)(opA + 32 + g * 8) = w;
    w.x = f2bf(oB0[g * 4 + 0] * liB); w.y = f2bf(oB0[g * 4 + 1] * liB);
    w.z = f2bf(oB0[g * 4 + 2] * liB); w.w = f2bf(oB0[g * 4 + 3] * liB);
    *(ushort4*)(opB + g * 8) = w;
    w.x = f2bf(oB1[g * 4 + 0] * liB); w.y = f2bf(oB1[g * 4 + 1] * liB);
    w.z = f2bf(oB1[g * 4 + 2] * liB); w.w = f2bf(oB1[g * 4 + 3] * liB);
    *(ushort4*)(opB + 32 + g * 8) = w;
  }
}

// ---------------------------------------------------------------- GEMM2 (out proj)
__global__ __launch_bounds__(256) void k_gemm2(const u16* __restrict__ A,
                                               const u16* __restrict__ Bt,
                                               float* __restrict__ C) {
  const int K = 1024, N = 1024;
  __shared__ u16 lA[128 * 64];
  __shared__ u16 lB[128 * 64];
  const int t = threadIdx.x;
  const int lane = t & 63;
  const int w = t >> 6;
  const int lg = lane >> 4, lr = lane & 15;
  const int wr = w >> 1, wc = w & 1;
  int f = blockIdx.x;
  int cpx = 256 >> 3;
  int f2 = (f & 7) * cpx + (f >> 3);
  const int n0 = (f2 & 7) * 128, m0 = (f2 >> 3) * 128;

  f32x4 acc[4][4];
#pragma unroll
  for (int a = 0; a < 4; ++a)
#pragma unroll
    for (int b = 0; b < 4; ++b) acc[a][b] = (f32x4)0.0f;

  for (int kt = 0; kt < K; kt += 64) {
#pragma unroll
    for (int i = 0; i < 4; ++i) {
      int c = t + i * 256;
      int row = c >> 3, slot = c & 7;
      int k8 = (slot ^ (row & 7)) << 3;
      __builtin_amdgcn_global_load_lds(
          (const __attribute__((address_space(1))) void*)(A + (size_t)(m0 + row) * K + kt + k8),
          (__attribute__((address_space(3))) void*)(&lA[c * 8]), 16, 0, 0);
    }
#pragma unroll
    for (int i = 0; i < 4; ++i) {
      int c = t + i * 256;
      int row = c >> 3, slot = c & 7;
      int k8 = (slot ^ (row & 7)) << 3;
      __builtin_amdgcn_global_load_lds(
          (const __attribute__((address_space(1))) void*)(Bt + (size_t)(n0 + row) * K + kt + k8),
          (__attribute__((address_space(3))) void*)(&lB[c * 8]), 16, 0, 0);
    }
    asm volatile("s_waitcnt vmcnt(0)" ::: "memory");
    __syncthreads();

#pragma unroll
    for (int ks = 0; ks < 2; ++ks) {
      bf16x8 af[4], bff[4];
#pragma unroll
      for (int mf = 0; mf < 4; ++mf) {
        int row = wr * 64 + mf * 16 + lr;
        int eo = (ks * 32 + lg * 8) ^ ((row & 7) << 3);
        af[mf] = ld_bf8(&lA[row * 64 + eo]);
      }
#pragma unroll
      for (int nf = 0; nf < 4; ++nf) {
        int row = wc * 64 + nf * 16 + lr;
        int eo = (ks * 32 + lg * 8) ^ ((row & 7) << 3);
        bff[nf] = ld_bf8(&lB[row * 64 + eo]);
      }
#pragma unroll
      for (int mf = 0; mf < 4; ++mf)
#pragma unroll
        for (int nf = 0; nf < 4; ++nf)
          acc[mf][nf] = MFMA16(af[mf], bff[nf], acc[mf][nf]);
    }
    __syncthreads();
  }

#pragma unroll
  for (int mf = 0; mf < 4; ++mf)
#pragma unroll
    for (int nf = 0; nf < 4; ++nf) {
      int col = n0 + wc * 64 + nf * 16 + lr;
#pragma unroll
      for (int i = 0; i < 4; ++i) {
        int row = m0 + wr * 64 + mf * 16 + lg * 4 + i;
        C[(size_t)row * N + col] = acc[mf][nf][i];
      }
    }
}

// ----------------------------------------------------------------------------
extern "C" void kernel_launch(void* const* d_in, const int* in_sizes, int n_in,
                              void* d_out, int out_size, void* d_ws, size_t ws_size,
                              hipStream_t stream) {
  const float* x  = (const float*)d_in[0];
  const float* Wq = (const float*)d_in[1];
  const float* Wk = (const float*)d_in[2];
  const float* Wv = (const float*)d_in[3];
  const float* Wo = (const float*)d_in[4];
  float* out = (float*)d_out;

  char* ws = (char*)d_ws;
  u16*    xb    = (u16*)(ws);                    //  8,388,608
  u16*    WqkvT = (u16*)(ws + 8388608);          //  3,145,728
  u16*    WoT   = (u16*)(ws + 11534336);         //  2,097,152
  float2* tab   = (float2*)(ws + 13631488);      //    524,288
  u16*    Qa    = (u16*)(ws + 14155776);         //  8,388,608
  u16*    Ka    = (u16*)(ws + 22544384);         //  2,097,152
  u16*    Vsd   = (u16*)(ws + 24641536);         //  2,097,152
  u16*    Vt    = (u16*)(ws + 26738688);         //  2,097,152
  u16*    Ob    = (u16*)(ws + 28835840);         //  8,388,608  (end 37,224,448)

  k_prep<<<4992, 256, 0, stream>>>((const float4*)x, (ushort4*)xb, Wq, Wk, Wv, Wo,
                                   WqkvT, WoT, tab);
  k_gemm1<<<384, 256, 0, stream>>>(xb, WqkvT, tab, Qa, Ka, Vsd);
  k_tv2<<<256, 256, 0, stream>>>(Vsd, Vt);
  k_attn<<<1024, 64, 0, stream>>>(Qa, Ka, Vt, Ob);
  k_gemm2<<<256, 256, 0, stream>>>(Ob, WoT, out);
}